// Round 1
// baseline (448.965 us; speedup 1.0000x reference)
//
#include <hip/hip_runtime.h>
#include <hip/hip_bf16.h>
#include <stdint.h>

// Problem constants
#define L_DIM 4096
#define B_DIM 32
#define H_DIM 512
#define M_DIM (L_DIM * B_DIM)  // 131072 rows of the fused GEMM
#define K_DIM H_DIM            // 512 reduction dim

typedef _Float16 half8 __attribute__((ext_vector_type(8)));
typedef __fp16 fp16x2 __attribute__((ext_vector_type(2)));  // cvt_pkrtz return type
typedef float floatx4 __attribute__((ext_vector_type(4)));

// tanh(x) = 1 - 2/(1 + e^{2x}), via hw exp2 + rcp (~1e-7 abs err, saturates correctly)
__device__ __forceinline__ float tanh_fast(float x) {
  float e = __builtin_amdgcn_exp2f(x * 2.88539008177793f);  // 2*log2(e)
  return 1.0f - 2.0f * __builtin_amdgcn_rcpf(e + 1.0f);
}

__device__ __forceinline__ uint2 pack4(const float4& f) {
  const fp16x2 p0 = __builtin_amdgcn_cvt_pkrtz(f.x, f.y);
  const fp16x2 p1 = __builtin_amdgcn_cvt_pkrtz(f.z, f.w);
  uint2 u;
  u.x = __builtin_bit_cast(unsigned, p0);
  u.y = __builtin_bit_cast(unsigned, p1);
  return u;
}

// ---------------------------------------------------------------------------
// Merged prep: blocks [0,128) build W2 (Wk fp16, MFMA-fragment-packed);
// blocks [128,160) compute q_proj (fp32, exact).
// W2 chunk c = ((kt*32 + nc)*4 + q)*16 + l15 holds Wk[k=kt*32+q*8+j][n=nc*16+l15].
__global__ __launch_bounds__(256) void prep_kernel(const float* __restrict__ query,
                                                   const float* __restrict__ W,
                                                   float* __restrict__ qp,
                                                   _Float16* __restrict__ W2) {
  if (blockIdx.x < 128) {
    // ---- wconv: Wk (=W[512:]) -> packed fp16 chunks
    const int t = blockIdx.x * 256 + threadIdx.x;  // [0, 32768) chunk index
    const int l15 = t & 15;
    const int q = (t >> 4) & 3;
    const int nc = (t >> 6) & 31;
    const int kt = t >> 11;
    const int n = nc * 16 + l15;
    const int kbase = H_DIM + kt * 32 + q * 8;  // Wk rows live at W[512 + k]
    half8 h;
#pragma unroll
    for (int j = 0; j < 8; ++j)
      h[j] = (_Float16)W[(size_t)(kbase + j) * H_DIM + n];
    *(half8*)(W2 + (size_t)t * 8) = h;
  } else if (threadIdx.x < 128) {
    // ---- qproj: q_proj[b][h] = sum_i query[b][i] * W[i][h]
    const int b = blockIdx.x - 128;
    const int h = threadIdx.x * 4;
    const float* qrow = query + b * H_DIM;
    float4 acc = make_float4(0.f, 0.f, 0.f, 0.f);
#pragma unroll 8
    for (int i = 0; i < K_DIM; ++i) {
      const float qv = qrow[i];
      const float4 w4 = *(const float4*)(W + (size_t)i * H_DIM + h);
      acc.x += qv * w4.x; acc.y += qv * w4.y;
      acc.z += qv * w4.z; acc.w += qv * w4.w;
    }
    *(float4*)(qp + (size_t)b * H_DIM + h) = acc;
  }
}

// ---------------------------------------------------------------------------
// Fused GEMM + tanh + v-dot. 128 rows x 512 cols per block (key read once),
// 512 threads = 8 waves, each wave owns a DISTINCT 64-col stripe (acc[8][4])
// so every W2 fragment is loaded exactly once per block -> B L2 traffic is
// 0.5 GiB total (was 1.0 GiB with 64-row blocks), below the HBM A-stream.
// A: LDS double-buffer (fp16, padded stride 40), ONE barrier/iter; global A
// loads are lane-contiguous 16B and prefetched 2 iters ahead; staging uses
// VGPR+ds_write so s_barrier needs no vmcnt drain -- global loads stay in
// flight across it. B: global->VGPR direct (W2 packed per-fragment),
// prefetched 1 iter ahead, L2-resident.
__global__ __launch_bounds__(512, 2) void fused_gemm_kernel(
    const float* __restrict__ key, const _Float16* __restrict__ W2,
    const float* __restrict__ qp, const float* __restrict__ v,
    float* __restrict__ scores) {
  __shared__ __align__(16) _Float16 As[2][128 * 40];  // pad 32->40: frag reads ~2-way
  __shared__ float swave[8 * 128];

  const int tid = threadIdx.x;
  const int lane = tid & 63;
  const int wn = tid >> 6;        // wave id = column stripe [0,8)
  const int l15 = lane & 15;
  const int quad = lane >> 4;
  const int m0 = blockIdx.x * 128;

  // A staging: thread t loads 16B chunk (t&7) of rows (t>>3) and (t>>3)+64
  const int ar = tid >> 3;       // 0..63
  const int aseg = tid & 7;      // 16B chunk within 128B k-slice
  const float* ag0 = key + (size_t)(m0 + ar) * K_DIM + aseg * 4;
  const float* ag1 = ag0 + (size_t)64 * K_DIM;
  const int adst0 = ar * 40 + aseg * 4;          // halves
  const int adst1 = (ar + 64) * 40 + aseg * 4;

  // B: chunk index for (kt, fn) = (kt*32 + wn*4 + fn)*64 + lane; 16B chunks
  const half8* bptr = (const half8*)W2 + (size_t)(wn * 4) * 64 + lane;

  // fragment LDS offsets (8 row-groups of 16)
  int aoff[8];
#pragma unroll
  for (int fm = 0; fm < 8; ++fm) aoff[fm] = (fm * 16 + l15) * 40 + quad * 8;

  floatx4 acc[8][4];
#pragma unroll
  for (int fm = 0; fm < 8; ++fm)
#pragma unroll
    for (int fn = 0; fn < 4; ++fn) acc[fm][fn] = (floatx4)0.0f;

  // prologue: A(0) -> LDS buf0; issue A(1), B(0)
  float4 ra0 = *(const float4*)(ag0);
  float4 ra1 = *(const float4*)(ag1);
  half8 bn[4];
#pragma unroll
  for (int fn = 0; fn < 4; ++fn) bn[fn] = bptr[fn * 64];
  bptr += 32 * 64;
  *(uint2*)(As[0] + adst0) = pack4(ra0);
  *(uint2*)(As[0] + adst1) = pack4(ra1);
  ra0 = *(const float4*)(ag0 + 32);
  ra1 = *(const float4*)(ag1 + 32);
  __syncthreads();

  for (int kt = 0; kt < 16; ++kt) {
    half8 bc[4];
#pragma unroll
    for (int fn = 0; fn < 4; ++fn) bc[fn] = bn[fn];
    if (kt < 15) {
      // issue B(kt+1) now, consume next iteration
#pragma unroll
      for (int fn = 0; fn < 4; ++fn) bn[fn] = bptr[fn * 64];
      bptr += 32 * 64;
    }
    // frag reads for this iteration (buf kt&1, written before last barrier)
    half8 av[8];
#pragma unroll
    for (int fm = 0; fm < 8; ++fm) av[fm] = *(const half8*)(As[kt & 1] + aoff[fm]);
    if (kt < 15) {
      // stage A(kt+1) into the other buffer (raw regs issued 2 iters ago)
      _Float16* dst = As[(kt + 1) & 1];
      *(uint2*)(dst + adst0) = pack4(ra0);
      *(uint2*)(dst + adst1) = pack4(ra1);
      if (kt < 14) {
        ra0 = *(const float4*)(ag0 + (kt + 2) * 32);
        ra1 = *(const float4*)(ag1 + (kt + 2) * 32);
      }
    }
#pragma unroll
    for (int fm = 0; fm < 8; ++fm)
#pragma unroll
      for (int fn = 0; fn < 4; ++fn)
        acc[fm][fn] = __builtin_amdgcn_mfma_f32_16x16x32_f16(av[fm], bc[fn],
                                                             acc[fm][fn], 0, 0, 0);
    __syncthreads();  // lgkmcnt only: outstanding global loads cross freely
  }

  // Epilogue: score[m] = sum_n v[n] * tanh(qp[m&31][n] + kproj[m][n])
  // C/D layout: col = lane&15, row = quad*4 + reg (verified: passes)
  float vv[4];
#pragma unroll
  for (int fn = 0; fn < 4; ++fn) vv[fn] = v[wn * 64 + fn * 16 + l15];

#pragma unroll
  for (int fm = 0; fm < 8; ++fm) {
#pragma unroll
    for (int r = 0; r < 4; ++r) {
      const int mrow = fm * 16 + quad * 4 + r;
      const float* qrow = qp + (size_t)(mrow & 31) * H_DIM;
      float rs = 0.f;
#pragma unroll
      for (int fn = 0; fn < 4; ++fn) {
        const int n = wn * 64 + fn * 16 + l15;
        const float x = qrow[n] + acc[fm][fn][r];
        rs += vv[fn] * tanh_fast(x);
      }
      rs += __shfl_xor(rs, 1);
      rs += __shfl_xor(rs, 2);
      rs += __shfl_xor(rs, 4);
      rs += __shfl_xor(rs, 8);
      if (l15 == 0) swave[wn * 128 + mrow] = rs;
    }
  }
  __syncthreads();
  if (tid < 128) {
    float s = 0.f;
#pragma unroll
    for (int j = 0; j < 8; ++j) s += swave[j * 128 + tid];
    const int m = m0 + tid;  // m = l*32 + b
    scores[(size_t)(m & 31) * L_DIM + (m >> 5)] = s;  // transposed: [b][l]
  }
}

// ---------------------------------------------------------------------------
// softmax over l per b; scores already [b][l]; out[b][l] — fully coalesced.
// Wave shfl reductions: 2 barriers instead of 16.
__global__ __launch_bounds__(256) void softmax_kernel(const float* __restrict__ scores,
                                                      float* __restrict__ out) {
  const int b = blockIdx.x;
  const int t = threadIdx.x;
  const int lane = t & 63;
  const int w = t >> 6;
  __shared__ float redm[4], reds[4];
  const float* srow = scores + (size_t)b * L_DIM;
  float s[16];
#pragma unroll
  for (int i = 0; i < 16; ++i) s[i] = srow[t + i * 256];
  float mx = s[0];
#pragma unroll
  for (int i = 1; i < 16; ++i) mx = fmaxf(mx, s[i]);
#pragma unroll
  for (int off = 1; off < 64; off <<= 1) mx = fmaxf(mx, __shfl_xor(mx, off));
  if (lane == 0) redm[w] = mx;
  __syncthreads();
  mx = fmaxf(fmaxf(redm[0], redm[1]), fmaxf(redm[2], redm[3]));
  float sum = 0.f;
#pragma unroll
  for (int i = 0; i < 16; ++i) {
    s[i] = __builtin_amdgcn_exp2f((s[i] - mx) * 1.44269504f);
    sum += s[i];
  }
#pragma unroll
  for (int off = 1; off < 64; off <<= 1) sum += __shfl_xor(sum, off);
  if (lane == 0) reds[w] = sum;
  __syncthreads();
  const float inv = 1.0f / (reds[0] + reds[1] + reds[2] + reds[3]);
#pragma unroll
  for (int i = 0; i < 16; ++i) out[(size_t)b * L_DIM + t + i * 256] = s[i] * inv;
}

// ---------------------------------------------------------------------------
extern "C" void kernel_launch(void* const* d_in, const int* in_sizes, int n_in,
                              void* d_out, int out_size, void* d_ws, size_t ws_size,
                              hipStream_t stream) {
  const float* query = (const float*)d_in[0];
  const float* key   = (const float*)d_in[1];
  const float* W     = (const float*)d_in[2];
  const float* v     = (const float*)d_in[3];
  float* out = (float*)d_out;

  char* ws = (char*)d_ws;
  float* qp       = (float*)ws;                        // 32*512*4   = 64 KB
  float* scores   = (float*)(ws + 65536);              // 131072*4   = 512 KB
  _Float16* W2    = (_Float16*)(ws + 65536 + 524288);  // 512*512*2  = 512 KB

  prep_kernel<<<160, 256, 0, stream>>>(query, W, qp, W2);
  fused_gemm_kernel<<<M_DIM / 128, 512, 0, stream>>>(key, W2, qp, v, scores);
  softmax_kernel<<<B_DIM, 256, 0, stream>>>(scores, out);
}